// Round 8
// baseline (866.373 us; speedup 1.0000x reference)
//
#include <hip/hip_runtime.h>
#include <stdint.h>

#define M_TOK 2048
#define HID   1024
#define NEXP  64
#define TOPK  6
#define TOTSLOT (M_TOK*TOPK)   // 12288

typedef unsigned short u16;
typedef __attribute__((ext_vector_type(4))) u16   u16x4;
typedef __attribute__((ext_vector_type(8))) u16   u16x8;
typedef __attribute__((ext_vector_type(4))) float f32x4;
typedef __attribute__((ext_vector_type(8))) short bf16x8;

__device__ __forceinline__ u16 f2b(float f) {
    union { float f; uint32_t u; } v; v.f = f;
    uint32_t r = v.u + 0x7FFFu + ((v.u >> 16) & 1u);
    return (u16)(r >> 16);
}
__device__ __forceinline__ float b2f(u16 b) {
    union { uint32_t u; float f; } v; v.u = ((uint32_t)b) << 16; return v.f;
}

// ---------------- x fp32 -> bf16 ----------------
__global__ __launch_bounds__(256) void convert_x_kernel(const float* __restrict__ x,
                                                        u16* __restrict__ xb) {
    int i = (blockIdx.x * 256 + threadIdx.x) * 4;
    float4 v = *reinterpret_cast<const float4*>(x + i);
    u16x4 o; o[0] = f2b(v.x); o[1] = f2b(v.y); o[2] = f2b(v.z); o[3] = f2b(v.w);
    *reinterpret_cast<u16x4*>(xb + i) = o;
}

// ---------------- gw transpose: gwT[k][e] so router lanes read coalesced ----------------
__global__ __launch_bounds__(256) void transpose_gw_kernel(const float* __restrict__ gw,
                                                           float* __restrict__ gwT) {
    int i = blockIdx.x * 256 + threadIdx.x;   // 65536 elements
    int e = i >> 10, k = i & 1023;
    gwT[k * NEXP + e] = gw[i];
}

// ---------------- router: fp64 logits (coalesced gwT), grouped topk ----------------
__global__ __launch_bounds__(64) void router_kernel(
    const float* __restrict__ x, const float* __restrict__ gwT,
    int* __restrict__ topk_id, float* __restrict__ topk_w, int* __restrict__ counts)
{
    int t = blockIdx.x, lane = threadIdx.x;
    __shared__ float xr[HID];
    for (int k = lane; k < HID; k += 64) xr[k] = x[(size_t)t * HID + k];
    __syncthreads();
    double s0 = 0.0, s1 = 0.0, s2 = 0.0, s3 = 0.0;
    for (int k = 0; k < HID; k += 4) {
        s0 += (double)xr[k]   * (double)gwT[(k)   * NEXP + lane];
        s1 += (double)xr[k+1] * (double)gwT[(k+1) * NEXP + lane];
        s2 += (double)xr[k+2] * (double)gwT[(k+2) * NEXP + lane];
        s3 += (double)xr[k+3] * (double)gwT[(k+3) * NEXP + lane];
    }
    double s = (s0 + s1) + (s2 + s3);
    __shared__ double lg[NEXP];
    __shared__ float  pr[NEXP];
    float sf = (float)s;
    float mx = sf;
    for (int o = 32; o; o >>= 1) mx = fmaxf(mx, __shfl_xor(mx, o));
    float ev = __expf(sf - mx);
    float sum = ev;
    for (int o = 32; o; o >>= 1) sum += __shfl_xor(sum, o);
    lg[lane] = s; pr[lane] = ev / sum;
    __syncthreads();
    if (lane == 0) {
        double gs[8];
        #pragma unroll
        for (int g = 0; g < 8; ++g) {
            double m = lg[g*8];
            #pragma unroll
            for (int i = 1; i < 8; ++i) m = fmax(m, lg[g*8+i]);
            gs[g] = m;
        }
        unsigned gsel = 0;
        for (int r = 0; r < 3; ++r) {
            int bi = 0; double bv = -1e300;
            for (int g = 0; g < 8; ++g)
                if (!((gsel>>g)&1u) && gs[g] > bv) { bv = gs[g]; bi = g; }
            gsel |= 1u << bi;
        }
        unsigned long long taken = 0;
        for (int r = 0; r < TOPK; ++r) {
            int bi = 0; double bv = -1e300;
            for (int e = 0; e < NEXP; ++e) {
                if (!((gsel >> (e>>3)) & 1u)) continue;
                if ((taken >> e) & 1ull) continue;
                if (lg[e] > bv) { bv = lg[e]; bi = e; }
            }
            taken |= 1ull << bi;
            topk_id[t*TOPK + r] = bi;
            topk_w[t*TOPK + r] = pr[bi];
            atomicAdd(&counts[bi], 1);
        }
    }
}

__global__ void scan_kernel(const int* __restrict__ counts, int* __restrict__ offs,
                            int* __restrict__ cursor) {
    if (threadIdx.x == 0) {
        int acc = 0;
        for (int e = 0; e < NEXP; ++e) { offs[e] = acc; cursor[e] = acc; acc += counts[e]; }
        offs[NEXP] = acc;
    }
}

__global__ __launch_bounds__(256) void fill_kernel(
    const int* __restrict__ topk_id, const float* __restrict__ topk_w,
    int* __restrict__ cursor, int* __restrict__ stok, float* __restrict__ sw,
    int* __restrict__ spos)
{
    int idx = blockIdx.x*256 + threadIdx.x;
    if (idx >= TOTSLOT) return;
    int e = topk_id[idx];
    int pos = atomicAdd(&cursor[e], 1);
    stok[pos] = idx / TOPK;
    sw[pos] = topk_w[idx];
    spos[idx] = pos;
}

#define SBAR() __builtin_amdgcn_sched_barrier(0)

// ---------------- unified MFMA GEMM: BM=256, BK=32, 512 thr, 2 blocks/CU ----------------
// KIND 0: routed gate/up  BN=128  DEEP  A=x_bf16[tok] K=1024, B=w1[e] -> h (silu*up*w)
// KIND 1: shared gate/up  BN=128  DEEP  A=x_bf16     K=1024, B=sgu  -> hs
// KIND 2: routed down     BN=128  DEEP  A=h          K=1024, B=w2[e]-> y
// KIND 3: shared down     BN=64  simple A=hs         K=2048, B=sdn  -> Out (f32)
// DEEP: brs[4] reg B-prefetch (4 ahead) + A 3-slot LDS ring (2 ahead) + counted
// vmcnt(8) + raw s_barrier (loads stay in flight across barriers; T3/T4).
template<int KIND>
__global__ __launch_bounds__(512, 4) void gemm_kernel(
    const u16* __restrict__ A, const float* __restrict__ Bw,
    u16* __restrict__ Hout, float* __restrict__ Out,
    const int* __restrict__ offs, const int* __restrict__ stok,
    const float* __restrict__ sw)
{
    constexpr bool G1     = (KIND == 0 || KIND == 1);
    constexpr bool ROUTED = (KIND == 0 || KIND == 2);
    constexpr bool DEEP   = (KIND != 3);
    constexpr int  BM     = 256;
    constexpr int  BN     = (KIND == 3) ? 64 : 128;
    constexpr int  NF     = BN / 16;
    constexpr int  KD     = (KIND == 3) ? 2048 : 1024;
    constexpr int  KITER  = KD / 32;
    constexpr int  NPAIR  = (KIND == 0) ? 1024 : 2048;
    constexpr int  TPR    = 512 / BN;     // B-stage threads per row (4 or 8)
    constexpr int  CPT    = 32 / TPR;     // B fp32 cols per thread (8 or 4)
    constexpr int  BREG   = CPT / 4;      // float4 per set (2 or 1)
    constexpr int  NSLOT  = DEEP ? 3 : 2;

    __shared__ u16 As[NSLOT][BM*32];      // 48 KB deep / 32 KB simple
    __shared__ u16 Bs[2][BN*32];          // 16 KB (8 KB kind 3)
    __shared__ int   tkl[ROUTED ? BM : 1];
    __shared__ float swl[(KIND == 0) ? BM : 1];

    const int tid  = threadIdx.x;
    const int lane = tid & 63;
    const int wv   = tid >> 6;

    const int e = ROUTED ? blockIdx.z : 0;
    int off = 0, cnt = M_TOK;
    if (ROUTED) { off = offs[e]; cnt = offs[e+1] - off; }
    const int m0 = blockIdx.y * BM;
    if (m0 >= cnt) return;
    const int nblk = blockIdx.x;

    if (ROUTED && tid < BM) {
        int gr = m0 + tid;
        if (KIND == 0) {
            tkl[tid] = (gr < cnt) ? stok[off + gr] : 0;
            swl[tid] = (gr < cnt) ? sw[off + gr] : 0.f;
        } else {
            int r = off + gr; if (r > TOTSLOT-1) r = TOTSLOT-1;
            tkl[tid] = r;
        }
    }
    __syncthreads();

    // A staging addressing (verified R7): pre-swizzled source chunk, linear LDS dest
    const int acol8 = (lane & 3) ^ ((lane >> 3) & 3);
    int aoff[2];
    #pragma unroll
    for (int j = 0; j < 2; ++j) {
        int r = wv*32 + j*16 + (lane >> 2);
        int arow = ROUTED ? tkl[r] : (m0 + r);
        aoff[j] = arow * KD + acol8 * 8;
    }

    const float* Be = Bw;
    if (KIND == 0) Be += (size_t)e * (size_t)(2*1024*1024);
    if (KIND == 2) Be += (size_t)e * (size_t)(1024*1024);
    const int rb = tid / TPR;
    const int q  = tid % TPR;
    int brow;
    if (G1) brow = (rb < 64) ? (nblk*64 + rb) : (NPAIR + nblk*64 + (rb - 64));
    else    brow = nblk*BN + rb;
    const float* bsrc = Be + (size_t)brow * KD + q*CPT;

    auto stageA = [&](int slot, int k0) {
        u16* abase = &As[0][0] + slot * (BM*32);
        #pragma unroll
        for (int j = 0; j < 2; ++j) {
            __builtin_amdgcn_global_load_lds(
                (const __attribute__((address_space(1))) uint32_t*)(A + (size_t)(aoff[j] + k0)),
                (__attribute__((address_space(3))) uint32_t*)(&abase[(wv*32 + j*16)*32]),
                16, 0, 0);
        }
    };
    auto loadB = [&](float4 (&br)[BREG], int k0) {
        #pragma unroll
        for (int j = 0; j < BREG; ++j)
            br[j] = *reinterpret_cast<const float4*>(bsrc + k0 + j*4);
    };
    auto storeB = [&](const float4 (&br)[BREG], int buf) {
        char* bd = (char*)&Bs[buf][0] + rb*64;
        if constexpr (CPT == 8) {
            u16x8 w;
            w[0] = f2b(br[0].x); w[1] = f2b(br[0].y); w[2] = f2b(br[0].z); w[3] = f2b(br[0].w);
            w[4] = f2b(br[1].x); w[5] = f2b(br[1].y); w[6] = f2b(br[1].z); w[7] = f2b(br[1].w);
            *reinterpret_cast<u16x8*>(bd + ((q ^ ((rb >> 1) & 3)) << 4)) = w;
        } else {
            u16x4 w;
            w[0] = f2b(br[0].x); w[1] = f2b(br[0].y); w[2] = f2b(br[0].z); w[3] = f2b(br[0].w);
            *reinterpret_cast<u16x4*>(bd + (((q>>1) ^ ((rb >> 1) & 3)) << 4) + (q & 1) * 8) = w;
        }
    };

    f32x4 acc[2][NF];
    #pragma unroll
    for (int mf = 0; mf < 2; ++mf)
        #pragma unroll
        for (int nf = 0; nf < NF; ++nf)
            acc[mf][nf] = (f32x4){0.f, 0.f, 0.f, 0.f};

    const int slot = lane >> 4;
    const int xoff = ((slot ^ (((lane & 15) >> 1) & 3)) << 4);

    auto mfma_phase = [&](int aslot, int bbuf) {
        const u16* abase = &As[0][0] + aslot * (BM*32);
        bf16x8 af[2];
        #pragma unroll
        for (int mf = 0; mf < 2; ++mf) {
            int row = wv*32 + mf*16 + (lane & 15);
            af[mf] = *reinterpret_cast<const bf16x8*>((const char*)abase + row*64 + xoff);
        }
        #pragma unroll
        for (int nf = 0; nf < NF; ++nf) {
            int rowb = nf*16 + (lane & 15);
            bf16x8 bfr = *reinterpret_cast<const bf16x8*>((const char*)&Bs[bbuf][0] + rowb*64 + xoff);
            #pragma unroll
            for (int mf = 0; mf < 2; ++mf)
                acc[mf][nf] = __builtin_amdgcn_mfma_f32_16x16x32_bf16(af[mf], bfr, acc[mf][nf], 0, 0, 0);
        }
    };

    if constexpr (DEEP) {
        float4 brs[4][BREG];
        // prologue: B tiles 0-3 to regs, A tiles 0,1 staged; interleaved for FIFO math
        loadB(brs[0], 0);  SBAR(); stageA(0, 0);  SBAR();
        loadB(brs[1], 32); SBAR(); stageA(1, 32); SBAR();
        loadB(brs[2], 64); SBAR(); loadB(brs[3], 96); SBAR();
        asm volatile("s_waitcnt vmcnt(8)" ::: "memory");  // b0,A0 retired
        SBAR();
        storeB(brs[0], 0);
        asm volatile("s_waitcnt lgkmcnt(0)" ::: "memory");
        SBAR();
        __builtin_amdgcn_s_barrier();

        int slA = 2;   // stage slot for tile t+2
        int slC = 0;   // MFMA slot for tile t

#define PIPE_STEP(T, LU, SU)                                              \
        {                                                                 \
            const int t_ = (T);                                           \
            int kb = t_ + 4; if (kb > KITER-1) kb = KITER-1;              \
            int ka = t_ + 2; if (ka > KITER-1) ka = KITER-1;              \
            loadB(brs[LU], kb*32); SBAR();                                \
            stageA(slA, ka*32);    SBAR();                                \
            asm volatile("s_waitcnt vmcnt(8)" ::: "memory");              \
            SBAR();                                                       \
            if (t_ + 1 < KITER) storeB(brs[SU], (t_+1) & 1);              \
            mfma_phase(slC, t_ & 1);                                      \
            asm volatile("s_waitcnt lgkmcnt(0)" ::: "memory");            \
            SBAR();                                                       \
            __builtin_amdgcn_s_barrier();                                 \
            slA = (slA + 1 == 3) ? 0 : slA + 1;                           \
            slC = (slC + 1 == 3) ? 0 : slC + 1;                           \
        }

        for (int base = 0; base < KITER; base += 4) {
            PIPE_STEP(base + 0, 0, 1);
            PIPE_STEP(base + 1, 1, 2);
            PIPE_STEP(base + 2, 2, 3);
            PIPE_STEP(base + 3, 3, 0);
        }
#undef PIPE_STEP
    } else {
        float4 br[BREG];
        stageA(0, 0);
        loadB(br, 0);
        storeB(br, 0);
        __syncthreads();
        for (int kt = 0; kt < KITER; ++kt) {
            const int cur = kt & 1, nxt = cur ^ 1;
            const bool more = (kt + 1 < KITER);
            if (more) { stageA(nxt, (kt + 1) * 32); loadB(br, (kt + 1) * 32); }
            mfma_phase(cur, cur);
            if (more) storeB(br, nxt);
            __syncthreads();
        }
    }

    if constexpr (G1) {
        const int colbase = nblk*64 + (lane & 15);
        #pragma unroll
        for (int mf = 0; mf < 2; ++mf) {
            #pragma unroll
            for (int j = 0; j < 4; ++j) {
                int r = wv*32 + mf*16 + (lane >> 4)*4 + j;
                if (ROUTED && (m0 + r) >= cnt) continue;
                float wgt = (KIND == 0) ? swl[r] : 1.0f;
                size_t orow = (size_t)(ROUTED ? (off + m0 + r) : (m0 + r));
                #pragma unroll
                for (int nf = 0; nf < 4; ++nf) {
                    float g = acc[mf][nf][j];
                    float u = acc[mf][nf+4][j];
                    float hv = (g / (1.f + __expf(-g))) * u * wgt;
                    Hout[orow * NPAIR + colbase + nf*16] = f2b(hv);
                }
            }
        }
    } else {
        const int colbase = nblk*BN + (lane & 15);
        #pragma unroll
        for (int mf = 0; mf < 2; ++mf) {
            #pragma unroll
            for (int j = 0; j < 4; ++j) {
                int r = wv*32 + mf*16 + (lane >> 4)*4 + j;
                if (ROUTED && (m0 + r) >= cnt) continue;
                #pragma unroll
                for (int nf = 0; nf < NF; ++nf) {
                    float v = acc[mf][nf][j];
                    if (KIND == 2) Hout[(size_t)(off + m0 + r) * HID + colbase + nf*16] = f2b(v);
                    else           Out[(size_t)(m0 + r) * HID + colbase + nf*16] = v;
                }
            }
        }
    }
}

// ---------------- gather-reduce: out[t] += sum_k y[spos[t,k]] ----------------
__global__ __launch_bounds__(256) void reduce_kernel(
    const u16* __restrict__ y, const int* __restrict__ spos, float* __restrict__ out)
{
    int t = blockIdx.x;
    int c = threadIdx.x * 4;
    float4 o = *reinterpret_cast<const float4*>(out + (size_t)t*HID + c);
    #pragma unroll
    for (int k = 0; k < TOPK; ++k) {
        int p = spos[t*TOPK + k];
        u16x4 v = *reinterpret_cast<const u16x4*>(y + (size_t)p*HID + c);
        o.x += b2f(v[0]); o.y += b2f(v[1]); o.z += b2f(v[2]); o.w += b2f(v[3]);
    }
    *reinterpret_cast<float4*>(out + (size_t)t*HID + c) = o;
}

extern "C" void kernel_launch(void* const* d_in, const int* in_sizes, int n_in,
                              void* d_out, int out_size, void* d_ws, size_t ws_size,
                              hipStream_t stream)
{
    const float* x   = (const float*)d_in[0];
    const float* gw  = (const float*)d_in[1];
    const float* w1  = (const float*)d_in[2];
    const float* w2  = (const float*)d_in[3];
    const float* sgu = (const float*)d_in[4];
    const float* sdn = (const float*)d_in[5];
    float* out = (float*)d_out;

    char* p = (char*)d_ws;
    auto carve = [&](size_t bytes) { char* r = p; p += (bytes + 255) & ~(size_t)255; return r; };
    u16*   xb      = (u16*)  carve((size_t)M_TOK * HID * 2);
    u16*   h       = (u16*)  carve((size_t)TOTSLOT * 1024 * 2);
    u16*   hs      = (u16*)  carve((size_t)M_TOK * 2048 * 2);
    u16*   y       = (u16*)  carve((size_t)TOTSLOT * HID * 2);
    float* gwT     = (float*)carve((size_t)HID * NEXP * 4);
    int*   topk_id = (int*)  carve(M_TOK * TOPK * 4);
    float* topk_w  = (float*)carve(M_TOK * TOPK * 4);
    int*   counts  = (int*)  carve(NEXP * 4);
    int*   offs    = (int*)  carve((NEXP + 1) * 4);
    int*   cursor  = (int*)  carve(NEXP * 4);
    int*   stok    = (int*)  carve(TOTSLOT * 4);
    float* sw      = (float*)carve(TOTSLOT * 4);
    int*   spos    = (int*)  carve(TOTSLOT * 4);

    hipMemsetAsync(counts, 0, NEXP * 4, stream);
    convert_x_kernel<<<(M_TOK*HID/4 + 255)/256, 256, 0, stream>>>(x, xb);
    transpose_gw_kernel<<<(NEXP*HID + 255)/256, 256, 0, stream>>>(gw, gwT);
    router_kernel<<<M_TOK, 64, 0, stream>>>(x, gwT, topk_id, topk_w, counts);
    scan_kernel<<<1, 64, 0, stream>>>(counts, offs, cursor);
    fill_kernel<<<(TOTSLOT + 255)/256, 256, 0, stream>>>(topk_id, topk_w, cursor, stok, sw, spos);

    // shared expert path (writes d_out fully), routed experts into y, then gather
    gemm_kernel<1><<<dim3(32,8,1),  512, 0, stream>>>(xb, sgu, hs, nullptr, nullptr, nullptr, nullptr);
    gemm_kernel<3><<<dim3(16,8,1),  512, 0, stream>>>(hs, sdn, nullptr, out, nullptr, nullptr, nullptr);
    gemm_kernel<0><<<dim3(16,2,64), 512, 0, stream>>>(xb, w1, h, nullptr, offs, stok, sw);
    gemm_kernel<2><<<dim3(8,2,64),  512, 0, stream>>>(h, w2, y, nullptr, offs, stok, sw);
    reduce_kernel<<<M_TOK, 256, 0, stream>>>(y, spos, out);
}

// Round 9
// 656.515 us; speedup vs baseline: 1.3197x; 1.3197x over previous
//
#include <hip/hip_runtime.h>
#include <stdint.h>

#define M_TOK 2048
#define HID   1024
#define NEXP  64
#define TOPK  6
#define TOTSLOT (M_TOK*TOPK)   // 12288

typedef unsigned short u16;
typedef __attribute__((ext_vector_type(4))) u16   u16x4;
typedef __attribute__((ext_vector_type(8))) u16   u16x8;
typedef __attribute__((ext_vector_type(4))) float f32x4;
typedef __attribute__((ext_vector_type(8))) short bf16x8;

__device__ __forceinline__ u16 f2b(float f) {
    union { float f; uint32_t u; } v; v.f = f;
    uint32_t r = v.u + 0x7FFFu + ((v.u >> 16) & 1u);
    return (u16)(r >> 16);
}
__device__ __forceinline__ float b2f(u16 b) {
    union { uint32_t u; float f; } v; v.u = ((uint32_t)b) << 16; return v.f;
}

// ---------------- x fp32 -> bf16 ----------------
__global__ __launch_bounds__(256) void convert_x_kernel(const float* __restrict__ x,
                                                        u16* __restrict__ xb) {
    int i = (blockIdx.x * 256 + threadIdx.x) * 4;
    float4 v = *reinterpret_cast<const float4*>(x + i);
    u16x4 o; o[0] = f2b(v.x); o[1] = f2b(v.y); o[2] = f2b(v.z); o[3] = f2b(v.w);
    *reinterpret_cast<u16x4*>(xb + i) = o;
}

// ---------------- gw transpose: gwT[k][e] so router lanes read coalesced ----------------
__global__ __launch_bounds__(256) void transpose_gw_kernel(const float* __restrict__ gw,
                                                           float* __restrict__ gwT) {
    int i = blockIdx.x * 256 + threadIdx.x;   // 65536 elements
    int e = i >> 10, k = i & 1023;
    gwT[k * NEXP + e] = gw[i];
}

// ---------------- router: fp64 logits (coalesced gwT), grouped topk ----------------
__global__ __launch_bounds__(64) void router_kernel(
    const float* __restrict__ x, const float* __restrict__ gwT,
    int* __restrict__ topk_id, float* __restrict__ topk_w, int* __restrict__ counts)
{
    int t = blockIdx.x, lane = threadIdx.x;
    __shared__ float xr[HID];
    for (int k = lane; k < HID; k += 64) xr[k] = x[(size_t)t * HID + k];
    __syncthreads();
    double s0 = 0.0, s1 = 0.0, s2 = 0.0, s3 = 0.0;
    for (int k = 0; k < HID; k += 4) {
        s0 += (double)xr[k]   * (double)gwT[(k)   * NEXP + lane];
        s1 += (double)xr[k+1] * (double)gwT[(k+1) * NEXP + lane];
        s2 += (double)xr[k+2] * (double)gwT[(k+2) * NEXP + lane];
        s3 += (double)xr[k+3] * (double)gwT[(k+3) * NEXP + lane];
    }
    double s = (s0 + s1) + (s2 + s3);
    __shared__ double lg[NEXP];
    __shared__ float  pr[NEXP];
    float sf = (float)s;
    float mx = sf;
    for (int o = 32; o; o >>= 1) mx = fmaxf(mx, __shfl_xor(mx, o));
    float ev = __expf(sf - mx);
    float sum = ev;
    for (int o = 32; o; o >>= 1) sum += __shfl_xor(sum, o);
    lg[lane] = s; pr[lane] = ev / sum;
    __syncthreads();
    if (lane == 0) {
        double gs[8];
        #pragma unroll
        for (int g = 0; g < 8; ++g) {
            double m = lg[g*8];
            #pragma unroll
            for (int i = 1; i < 8; ++i) m = fmax(m, lg[g*8+i]);
            gs[g] = m;
        }
        unsigned gsel = 0;
        for (int r = 0; r < 3; ++r) {
            int bi = 0; double bv = -1e300;
            for (int g = 0; g < 8; ++g)
                if (!((gsel>>g)&1u) && gs[g] > bv) { bv = gs[g]; bi = g; }
            gsel |= 1u << bi;
        }
        unsigned long long taken = 0;
        for (int r = 0; r < TOPK; ++r) {
            int bi = 0; double bv = -1e300;
            for (int e = 0; e < NEXP; ++e) {
                if (!((gsel >> (e>>3)) & 1u)) continue;
                if ((taken >> e) & 1ull) continue;
                if (lg[e] > bv) { bv = lg[e]; bi = e; }
            }
            taken |= 1ull << bi;
            topk_id[t*TOPK + r] = bi;
            topk_w[t*TOPK + r] = pr[bi];
            atomicAdd(&counts[bi], 1);
        }
    }
}

__global__ void scan_kernel(const int* __restrict__ counts, int* __restrict__ offs,
                            int* __restrict__ cursor) {
    if (threadIdx.x == 0) {
        int acc = 0;
        for (int e = 0; e < NEXP; ++e) { offs[e] = acc; cursor[e] = acc; acc += counts[e]; }
        offs[NEXP] = acc;
    }
}

__global__ __launch_bounds__(256) void fill_kernel(
    const int* __restrict__ topk_id, const float* __restrict__ topk_w,
    int* __restrict__ cursor, int* __restrict__ stok, float* __restrict__ sw,
    int* __restrict__ spos)
{
    int idx = blockIdx.x*256 + threadIdx.x;
    if (idx >= TOTSLOT) return;
    int e = topk_id[idx];
    int pos = atomicAdd(&cursor[e], 1);
    stok[pos] = idx / TOPK;
    sw[pos] = topk_w[idx];
    spos[idx] = pos;
}

#define SBAR() __builtin_amdgcn_sched_barrier(0)

// ---------------- unified MFMA GEMM: BK=32, 512 thr ----------------
// KIND 0: routed gate/up  BM=256 BN=128 DEEP  A=x_bf16[tok] K=1024, B=w1[e] -> h
// KIND 1: shared gate/up  BM=256 BN=128 DEEP  A=x_bf16     K=1024, B=sgu  -> hs
// KIND 2: routed down     BM=256 BN=128 DEEP  A=h          K=1024, B=w2[e]-> y
// KIND 3: shared down     BM=128 BN=64 simple A=hs         K=2048, B=sdn  -> Out(f32)
// DEEP (T3/T4): B 2 reg-sets loaded 2 tiles ahead; A 3-slot LDS ring staged 2 ahead
// via global_load_lds; per-step s_waitcnt vmcnt(6) (never 0) + raw s_barrier.
template<int KIND>
__global__ __launch_bounds__(512, 4) void gemm_kernel(
    const u16* __restrict__ A, const float* __restrict__ Bw,
    u16* __restrict__ Hout, float* __restrict__ Out,
    const int* __restrict__ offs, const int* __restrict__ stok,
    const float* __restrict__ sw)
{
    constexpr bool G1     = (KIND == 0 || KIND == 1);
    constexpr bool ROUTED = (KIND == 0 || KIND == 2);
    constexpr bool DEEP   = (KIND != 3);
    constexpr int  BM     = DEEP ? 256 : 128;
    constexpr int  MR     = BM / 128;     // M fragments per wave (2 or 1)
    constexpr int  BN     = (KIND == 3) ? 64 : 128;
    constexpr int  NF     = BN / 16;
    constexpr int  KD     = (KIND == 3) ? 2048 : 1024;
    constexpr int  KITER  = KD / 32;
    constexpr int  NPAIR  = (KIND == 0) ? 1024 : 2048;
    constexpr int  TPR    = 512 / BN;     // B-stage threads per row (4 or 8)
    constexpr int  CPT    = 32 / TPR;     // B fp32 cols per thread (8 or 4)
    constexpr int  BREG   = CPT / 4;      // float4 per set (2 or 1)
    constexpr int  NSLOT  = DEEP ? 3 : 2;

    __shared__ u16 As[NSLOT][BM*32];      // 48 KB deep / 8 KB simple
    __shared__ u16 Bs[2][BN*32];          // 16 KB (8 KB kind 3)
    __shared__ int   tkl[ROUTED ? BM : 1];
    __shared__ float swl[(KIND == 0) ? BM : 1];

    const int tid  = threadIdx.x;
    const int lane = tid & 63;
    const int wv   = tid >> 6;

    const int e = ROUTED ? blockIdx.z : 0;
    int off = 0, cnt = M_TOK;
    if (ROUTED) { off = offs[e]; cnt = offs[e+1] - off; }
    const int m0 = blockIdx.y * BM;
    if (m0 >= cnt) return;
    const int nblk = blockIdx.x;

    if (ROUTED && tid < BM) {
        int gr = m0 + tid;
        if (KIND == 0) {
            tkl[tid] = (gr < cnt) ? stok[off + gr] : 0;
            swl[tid] = (gr < cnt) ? sw[off + gr] : 0.f;
        } else {
            int r = off + gr; if (r > TOTSLOT-1) r = TOTSLOT-1;
            tkl[tid] = r;
        }
    }
    __syncthreads();

    // A staging addressing (verified R7): pre-swizzled source chunk, linear LDS dest
    const int acol8 = (lane & 3) ^ ((lane >> 3) & 3);
    int aoff[MR];
    #pragma unroll
    for (int j = 0; j < MR; ++j) {
        int r = wv*(16*MR) + j*16 + (lane >> 2);
        int arow = ROUTED ? tkl[r] : (m0 + r);
        aoff[j] = arow * KD + acol8 * 8;
    }

    const float* Be = Bw;
    if (KIND == 0) Be += (size_t)e * (size_t)(2*1024*1024);
    if (KIND == 2) Be += (size_t)e * (size_t)(1024*1024);
    const int rb = tid / TPR;
    const int q  = tid % TPR;
    int brow;
    if (G1) brow = (rb < 64) ? (nblk*64 + rb) : (NPAIR + nblk*64 + (rb - 64));
    else    brow = nblk*BN + rb;
    const float* bsrc = Be + (size_t)brow * KD + q*CPT;

    auto stageA = [&](int slot, int k0) {
        u16* abase = &As[0][0] + slot * (BM*32);
        #pragma unroll
        for (int j = 0; j < MR; ++j) {
            __builtin_amdgcn_global_load_lds(
                (const __attribute__((address_space(1))) uint32_t*)(A + (size_t)(aoff[j] + k0)),
                (__attribute__((address_space(3))) uint32_t*)(&abase[(wv*(16*MR) + j*16)*32]),
                16, 0, 0);
        }
    };
    auto loadB = [&](float4 (&br)[BREG], int k0) {
        #pragma unroll
        for (int j = 0; j < BREG; ++j)
            br[j] = *reinterpret_cast<const float4*>(bsrc + k0 + j*4);
    };
    auto storeB = [&](const float4 (&br)[BREG], int buf) {
        char* bd = (char*)&Bs[buf][0] + rb*64;
        if constexpr (CPT == 8) {
            u16x8 w;
            w[0] = f2b(br[0].x); w[1] = f2b(br[0].y); w[2] = f2b(br[0].z); w[3] = f2b(br[0].w);
            w[4] = f2b(br[1].x); w[5] = f2b(br[1].y); w[6] = f2b(br[1].z); w[7] = f2b(br[1].w);
            *reinterpret_cast<u16x8*>(bd + ((q ^ ((rb >> 1) & 3)) << 4)) = w;
        } else {
            u16x4 w;
            w[0] = f2b(br[0].x); w[1] = f2b(br[0].y); w[2] = f2b(br[0].z); w[3] = f2b(br[0].w);
            *reinterpret_cast<u16x4*>(bd + (((q>>1) ^ ((rb >> 1) & 3)) << 4) + (q & 1) * 8) = w;
        }
    };

    f32x4 acc[MR][NF];
    #pragma unroll
    for (int mf = 0; mf < MR; ++mf)
        #pragma unroll
        for (int nf = 0; nf < NF; ++nf)
            acc[mf][nf] = (f32x4){0.f, 0.f, 0.f, 0.f};

    const int slot = lane >> 4;
    const int xoff = ((slot ^ (((lane & 15) >> 1) & 3)) << 4);

    auto mfma_phase = [&](int aslot, int bbuf) {
        const u16* abase = &As[0][0] + aslot * (BM*32);
        bf16x8 af[MR];
        #pragma unroll
        for (int mf = 0; mf < MR; ++mf) {
            int row = wv*(16*MR) + mf*16 + (lane & 15);
            af[mf] = *reinterpret_cast<const bf16x8*>((const char*)abase + row*64 + xoff);
        }
        #pragma unroll
        for (int nf = 0; nf < NF; ++nf) {
            int rowb = nf*16 + (lane & 15);
            bf16x8 bfr = *reinterpret_cast<const bf16x8*>((const char*)&Bs[bbuf][0] + rowb*64 + xoff);
            #pragma unroll
            for (int mf = 0; mf < MR; ++mf)
                acc[mf][nf] = __builtin_amdgcn_mfma_f32_16x16x32_bf16(af[mf], bfr, acc[mf][nf], 0, 0, 0);
        }
    };

    if constexpr (DEEP) {
        float4 setE[BREG], setO[BREG];
        // prologue: B tiles 0,1 -> regs; A tiles 0,1 -> slots 0,1 (8 vm ops)
        loadB(setE, 0);  SBAR();
        stageA(0, 0);    SBAR();
        loadB(setO, 32); SBAR();
        stageA(1, 32);   SBAR();
        asm volatile("s_waitcnt vmcnt(6)" ::: "memory");  // setE + A0 retired
        SBAR();
        storeB(setE, 0);
        asm volatile("s_waitcnt lgkmcnt(0)" ::: "memory");
        SBAR();
        __builtin_amdgcn_s_barrier();

        int slA = 2;   // stage slot for tile kt+2
        int slC = 0;   // MFMA slot for tile kt

#define STEP(KT, SLOAD, SSTORE)                                           \
        {                                                                 \
            int kpf = (KT) + 2; if (kpf > KITER-1) kpf = KITER-1;         \
            loadB(SLOAD, kpf*32);  SBAR();                                \
            stageA(slA, kpf*32);   SBAR();                                \
            asm volatile("s_waitcnt vmcnt(6)" ::: "memory");              \
            SBAR();                                                       \
            if ((KT) + 1 < KITER) storeB(SSTORE, ((KT)+1) & 1);           \
            mfma_phase(slC, (KT) & 1);                                    \
            asm volatile("s_waitcnt lgkmcnt(0)" ::: "memory");            \
            SBAR();                                                       \
            __builtin_amdgcn_s_barrier();                                 \
            slA = (slA + 1 == 3) ? 0 : slA + 1;                           \
            slC = (slC + 1 == 3) ? 0 : slC + 1;                           \
        }

        for (int kt = 0; kt < KITER; kt += 2) {
            STEP(kt,     setE, setO);   // even: refill E (tile kt+2), store O (tile kt+1)
            STEP(kt + 1, setO, setE);   // odd:  refill O, store E
        }
#undef STEP
    } else {
        float4 br[BREG];
        stageA(0, 0);
        loadB(br, 0);
        storeB(br, 0);
        __syncthreads();
        for (int kt = 0; kt < KITER; ++kt) {
            const int cur = kt & 1, nxt = cur ^ 1;
            const bool more = (kt + 1 < KITER);
            if (more) { stageA(nxt, (kt + 1) * 32); loadB(br, (kt + 1) * 32); }
            mfma_phase(cur, cur);
            if (more) storeB(br, nxt);
            __syncthreads();
        }
    }

    if constexpr (G1) {
        const int colbase = nblk*64 + (lane & 15);
        #pragma unroll
        for (int mf = 0; mf < MR; ++mf) {
            #pragma unroll
            for (int j = 0; j < 4; ++j) {
                int r = wv*(16*MR) + mf*16 + (lane >> 4)*4 + j;
                if (ROUTED && (m0 + r) >= cnt) continue;
                float wgt = (KIND == 0) ? swl[r] : 1.0f;
                size_t orow = (size_t)(ROUTED ? (off + m0 + r) : (m0 + r));
                #pragma unroll
                for (int nf = 0; nf < 4; ++nf) {
                    float g = acc[mf][nf][j];
                    float u = acc[mf][nf+4][j];
                    float hv = (g / (1.f + __expf(-g))) * u * wgt;
                    Hout[orow * NPAIR + colbase + nf*16] = f2b(hv);
                }
            }
        }
    } else {
        const int colbase = nblk*BN + (lane & 15);
        #pragma unroll
        for (int mf = 0; mf < MR; ++mf) {
            #pragma unroll
            for (int j = 0; j < 4; ++j) {
                int r = wv*(16*MR) + mf*16 + (lane >> 4)*4 + j;
                if (ROUTED && (m0 + r) >= cnt) continue;
                #pragma unroll
                for (int nf = 0; nf < NF; ++nf) {
                    float v = acc[mf][nf][j];
                    if (KIND == 2) Hout[(size_t)(off + m0 + r) * HID + colbase + nf*16] = f2b(v);
                    else           Out[(size_t)(m0 + r) * HID + colbase + nf*16] = v;
                }
            }
        }
    }
}

// ---------------- gather-reduce: out[t] += sum_k y[spos[t,k]] ----------------
__global__ __launch_bounds__(256) void reduce_kernel(
    const u16* __restrict__ y, const int* __restrict__ spos, float* __restrict__ out)
{
    int t = blockIdx.x;
    int c = threadIdx.x * 4;
    float4 o = *reinterpret_cast<const float4*>(out + (size_t)t*HID + c);
    #pragma unroll
    for (int k = 0; k < TOPK; ++k) {
        int p = spos[t*TOPK + k];
        u16x4 v = *reinterpret_cast<const u16x4*>(y + (size_t)p*HID + c);
        o.x += b2f(v[0]); o.y += b2f(v[1]); o.z += b2f(v[2]); o.w += b2f(v[3]);
    }
    *reinterpret_cast<float4*>(out + (size_t)t*HID + c) = o;
}

extern "C" void kernel_launch(void* const* d_in, const int* in_sizes, int n_in,
                              void* d_out, int out_size, void* d_ws, size_t ws_size,
                              hipStream_t stream)
{
    const float* x   = (const float*)d_in[0];
    const float* gw  = (const float*)d_in[1];
    const float* w1  = (const float*)d_in[2];
    const float* w2  = (const float*)d_in[3];
    const float* sgu = (const float*)d_in[4];
    const float* sdn = (const float*)d_in[5];
    float* out = (float*)d_out;

    char* p = (char*)d_ws;
    auto carve = [&](size_t bytes) { char* r = p; p += (bytes + 255) & ~(size_t)255; return r; };
    u16*   xb      = (u16*)  carve((size_t)M_TOK * HID * 2);
    u16*   h       = (u16*)  carve((size_t)TOTSLOT * 1024 * 2);
    u16*   hs      = (u16*)  carve((size_t)M_TOK * 2048 * 2);
    u16*   y       = (u16*)  carve((size_t)TOTSLOT * HID * 2);
    float* gwT     = (float*)carve((size_t)HID * NEXP * 4);
    int*   topk_id = (int*)  carve(M_TOK * TOPK * 4);
    float* topk_w  = (float*)carve(M_TOK * TOPK * 4);
    int*   counts  = (int*)  carve(NEXP * 4);
    int*   offs    = (int*)  carve((NEXP + 1) * 4);
    int*   cursor  = (int*)  carve(NEXP * 4);
    int*   stok    = (int*)  carve(TOTSLOT * 4);
    float* sw      = (float*)carve(TOTSLOT * 4);
    int*   spos    = (int*)  carve(TOTSLOT * 4);

    hipMemsetAsync(counts, 0, NEXP * 4, stream);
    convert_x_kernel<<<(M_TOK*HID/4 + 255)/256, 256, 0, stream>>>(x, xb);
    transpose_gw_kernel<<<(NEXP*HID + 255)/256, 256, 0, stream>>>(gw, gwT);
    router_kernel<<<M_TOK, 64, 0, stream>>>(x, gwT, topk_id, topk_w, counts);
    scan_kernel<<<1, 64, 0, stream>>>(counts, offs, cursor);
    fill_kernel<<<(TOTSLOT + 255)/256, 256, 0, stream>>>(topk_id, topk_w, cursor, stok, sw, spos);

    // shared expert path (writes d_out fully), routed experts into y, then gather
    gemm_kernel<1><<<dim3(32,8,1),  512, 0, stream>>>(xb, sgu, hs, nullptr, nullptr, nullptr, nullptr);
    gemm_kernel<3><<<dim3(16,16,1), 512, 0, stream>>>(hs, sdn, nullptr, out, nullptr, nullptr, nullptr);
    gemm_kernel<0><<<dim3(16,2,64), 512, 0, stream>>>(xb, w1, h, nullptr, offs, stok, sw);
    gemm_kernel<2><<<dim3(8,2,64),  512, 0, stream>>>(h, w2, y, nullptr, offs, stok, sw);
    reduce_kernel<<<M_TOK, 256, 0, stream>>>(y, spos, out);
}